// Round 6
// baseline (1175.032 us; speedup 1.0000x reference)
//
#include <hip/hip_runtime.h>
#include <hip/hip_bf16.h>

typedef __hip_bfloat16 bf16;
typedef __attribute__((ext_vector_type(8))) short s16x8;
typedef __attribute__((ext_vector_type(4))) short s16x4;
typedef __attribute__((ext_vector_type(4))) float f32x4;

// Problem constants
#define BATCH 8
#define NH 8
#define NTOK 3137         // H*W+1
#define HD 96             // head dim
#define HH 56
#define WW 56
#define NKEY 785          // 28*28+1
#define DIMC 768
#define DIM3 2304
#define MROWS (BATCH * NTOK)   // 25096

__device__ __forceinline__ float b2f(bf16 x) { return __bfloat162float(x); }
__device__ __forceinline__ bf16 f2b(float x) { return __float2bfloat16(x); }
__device__ __forceinline__ float s2f(short s) {
  return __uint_as_float(((uint32_t)(uint16_t)s) << 16);
}
__device__ __forceinline__ short f2bs(float x) {
  bf16 h = __float2bfloat16(x);
  short s; __builtin_memcpy(&s, &h, 2); return s;
}
__device__ __forceinline__ void cvt2(uint32_t u, float& a, float& b) {
  a = __uint_as_float(u << 16);
  b = __uint_as_float(u & 0xFFFF0000u);
}
__device__ __forceinline__ void gload_lds16(const void* g, void* l) {
  __builtin_amdgcn_global_load_lds(
      (const __attribute__((address_space(1))) void*)g,
      (__attribute__((address_space(3))) void*)l, 16, 0, 0);
}

// ---------------- Kernel 0a: X fp32 -> bf16 ----------------
__global__ __launch_bounds__(256) void k_cvtX(const float* __restrict__ X,
                                              bf16* __restrict__ Xb, int n4) {
  for (int i = blockIdx.x * blockDim.x + threadIdx.x; i < n4;
       i += gridDim.x * blockDim.x) {
    float4 v = reinterpret_cast<const float4*>(X)[i];
    ushort4 o;
    o.x = (unsigned short)f2bs(v.x); o.y = (unsigned short)f2bs(v.y);
    o.z = (unsigned short)f2bs(v.z); o.w = (unsigned short)f2bs(v.w);
    reinterpret_cast<ushort4*>(Xb)[i] = o;
  }
}

// ---------------- Kernel 0b: W [768][2304] fp32 -> W^T [2304][768] bf16 ----------------
__global__ __launch_bounds__(256) void k_cvtW(const float* __restrict__ W,
                                              bf16* __restrict__ WbT) {
  __shared__ float T[64][65];
  const int n0 = blockIdx.x * 64;
  const int k0 = blockIdx.y * 64;
  const int tid = threadIdx.x;
#pragma unroll
  for (int i = 0; i < 16; i++) {
    int e = tid + i * 256;
    int r = e >> 6, c = e & 63;
    T[r][c] = W[(size_t)(k0 + r) * DIM3 + n0 + c];
  }
  __syncthreads();
#pragma unroll
  for (int i = 0; i < 16; i++) {
    int e = tid + i * 256;
    int r = e >> 6, c = e & 63;
    WbT[(size_t)(n0 + r) * DIMC + k0 + c] = f2b(T[c][r]);
  }
}

// ---------------- Kernel 1: QKV projection, bf16 MFMA (unchanged) ----------------
__global__ __launch_bounds__(256) void k_qkv_mfma(
    const bf16* __restrict__ Xb, const bf16* __restrict__ WbT,
    const float* __restrict__ bias,
    bf16* __restrict__ Q, bf16* __restrict__ K, bf16* __restrict__ V) {
  __shared__ __align__(16) short As[4 * 128 * 8];
  __shared__ __align__(16) short Bs[4 * 128 * 8];
  const int tid = threadIdx.x;
  const int wid = tid >> 6, lane = tid & 63;
  const int g = lane >> 4, kl = lane & 15;
  const int wm = wid >> 1, wn = wid & 1;
  const int row0 = blockIdx.y * 128;
  const int col0 = blockIdx.x * 128;

  f32x4 acc[4][4] = {};

  for (int k0 = 0; k0 < DIMC; k0 += 32) {
#pragma unroll
    for (int r = 0; r < 2; r++) {
      int slot = r * 256 + wid * 64 + lane;
      int sg = slot >> 7, sm = slot & 127;
      int mm = row0 + sm; if (mm > MROWS - 1) mm = MROWS - 1;
      const bf16* gpA = Xb + (size_t)mm * DIMC + k0 + sg * 8;
      short* lpA = As + ((r * 256 + wid * 64) << 3);
      gload_lds16(gpA, lpA);
      const bf16* gpB = WbT + (size_t)(col0 + sm) * DIMC + k0 + sg * 8;
      short* lpB = Bs + ((r * 256 + wid * 64) << 3);
      gload_lds16(gpB, lpB);
    }
    __syncthreads();

    s16x8 af[4], bf[4];
#pragma unroll
    for (int i = 0; i < 4; i++)
      af[i] = *(const s16x8*)&As[((g << 7) + wm * 64 + i * 16 + kl) << 3];
#pragma unroll
    for (int j = 0; j < 4; j++)
      bf[j] = *(const s16x8*)&Bs[((g << 7) + wn * 64 + j * 16 + kl) << 3];
#pragma unroll
    for (int i = 0; i < 4; i++)
#pragma unroll
      for (int j = 0; j < 4; j++)
        acc[i][j] = __builtin_amdgcn_mfma_f32_16x16x32_bf16(af[i], bf[j], acc[i][j], 0, 0, 0);
    __syncthreads();
  }

#pragma unroll
  for (int i = 0; i < 4; i++) {
    int mbase = row0 + wm * 64 + i * 16 + (lane >> 4) * 4;
#pragma unroll
    for (int j = 0; j < 4; j++) {
      int n = col0 + wn * 64 + j * 16 + kl;
      int s = n / DIMC, rr = n % DIMC;
      int h = rr / HD, c = rr % HD;
      bf16* dst = (s == 0) ? Q : (s == 1) ? K : V;
      float bv = bias[n];
#pragma unroll
      for (int r = 0; r < 4; r++) {
        int mm = mbase + r;
        if (mm >= MROWS) continue;
        int b = mm / NTOK, nt = mm % NTOK;
        dst[(((size_t)b * NH + h) * NTOK + nt) * HD + c] = f2b(acc[i][j][r] + bv);
      }
    }
  }
}

// ---------------- Kernel 2: depthwise 3x3 pool + LayerNorm (unchanged) ----------------
template <int STRIDE, int OH, int OW>
__global__ __launch_bounds__(64) void k_pool(
    const bf16* __restrict__ raw, const float* __restrict__ wgt,
    const float* __restrict__ gam, const float* __restrict__ bet,
    bf16* __restrict__ out) {
  const int ntok = OH * OW + 1;
  const int t = blockIdx.x % ntok;
  const int bh = blockIdx.x / ntok;
  const int lane = threadIdx.x;
  const bf16* src = raw + (size_t)bh * NTOK * HD;

  float v0 = 0.f, v1 = 0.f;
  if (t == 0) {
    v0 = b2f(src[lane]);
    if (lane < 32) v1 = b2f(src[64 + lane]);
  } else {
    int oy = (t - 1) / OW, ox = (t - 1) % OW;
#pragma unroll
    for (int dy = 0; dy < 3; dy++) {
      int iy = oy * STRIDE + dy - 1;
      if (iy < 0 || iy >= HH) continue;
#pragma unroll
      for (int dx = 0; dx < 3; dx++) {
        int ix = ox * STRIDE + dx - 1;
        if (ix < 0 || ix >= WW) continue;
        const bf16* p = src + (size_t)(1 + iy * WW + ix) * HD;
        const float* wp = wgt + (dy * 3 + dx) * HD;
        v0 += b2f(p[lane]) * wp[lane];
        if (lane < 32) v1 += b2f(p[64 + lane]) * wp[64 + lane];
      }
    }
  }
  float s = v0 + ((lane < 32) ? v1 : 0.f);
  float s2 = v0 * v0 + ((lane < 32) ? v1 * v1 : 0.f);
#pragma unroll
  for (int o = 32; o > 0; o >>= 1) {
    s += __shfl_xor(s, o);
    s2 += __shfl_xor(s2, o);
  }
  float mean = s * (1.f / 96.f);
  float var = s2 * (1.f / 96.f) - mean * mean;
  float rstd = rsqrtf(var + 1e-5f);

  bf16* dst = out + ((size_t)bh * ntok + t) * HD;
  dst[lane] = f2b((v0 - mean) * rstd * gam[lane] + bet[lane]);
  if (lane < 32) dst[64 + lane] = f2b((v1 - mean) * rstd * gam[64 + lane] + bet[64 + lane]);
}

// ---------------- Kernel 2b: rel-pos dot tables ----------------
// thread -> (row = bh*NTOK + q, j in 0..27); computes q . rel_pos_h[qy-2j+54]
// and q . rel_pos_w[qx-2j+54]; stores gathered RHg/RWg [bh*NTOK + q][28] bf16.
__global__ __launch_bounds__(256) void k_rel(
    const bf16* __restrict__ Qp, const float* __restrict__ relHt,
    const float* __restrict__ relWt, bf16* __restrict__ RHg,
    bf16* __restrict__ RWg) {
  size_t gid = (size_t)blockIdx.x * 256 + threadIdx.x;
  if (gid >= (size_t)BATCH * NH * NTOK * 28) return;
  int j = (int)(gid % 28);
  size_t row = gid / 28;             // bh*NTOK + q
  int q = (int)(row % NTOK);
  int qy, qx;
  if (q < 1) { qy = 0; qx = 0; }
  else { qy = (q - 1) / WW; qx = (q - 1) % WW; }
  int ih = qy - 2 * j + 54;          // in [0,109] for q>0
  int iw = qx - 2 * j + 54;
  if (ih < 0) ih = 0; if (ih > 110) ih = 110;
  if (iw < 0) iw = 0; if (iw > 110) iw = 110;

  const uint4* qr = (const uint4*)(Qp + row * HD);
  const float4* ph = (const float4*)(relHt + (size_t)ih * HD);
  const float4* pw = (const float4*)(relWt + (size_t)iw * HD);
  float dh = 0.f, dw = 0.f;
#pragma unroll
  for (int c8 = 0; c8 < 12; c8++) {
    uint4 u = qr[c8];
    float q0, q1, q2, q3, q4, q5, q6, q7;
    cvt2(u.x, q0, q1); cvt2(u.y, q2, q3);
    cvt2(u.z, q4, q5); cvt2(u.w, q6, q7);
    float4 h0 = ph[2 * c8], h1 = ph[2 * c8 + 1];
    float4 w0 = pw[2 * c8], w1 = pw[2 * c8 + 1];
    dh += q0 * h0.x + q1 * h0.y + q2 * h0.z + q3 * h0.w +
          q4 * h1.x + q5 * h1.y + q6 * h1.z + q7 * h1.w;
    dw += q0 * w0.x + q1 * w0.y + q2 * w0.z + q3 * w0.w +
          q4 * w1.x + q5 * w1.y + q6 * w1.z + q7 * w1.w;
  }
  RHg[row * 28 + j] = f2b(dh);
  RWg[row * 28 + j] = f2b(dw);
}

// ---------------- Kernel 3: MFMA flash attention v2 ----------------
// 39 KB LDS -> 4 blocks/CU; rel tables precomputed; Q direct from global;
// XCD-swizzled block order for KV L2 locality.
__global__ __launch_bounds__(256, 4) void k_attn(
    const bf16* __restrict__ Qp, const bf16* __restrict__ Kp,
    const bf16* __restrict__ Vp, const bf16* __restrict__ RHg,
    const bf16* __restrict__ RWg, float* __restrict__ out) {
  __shared__ __align__(16) short Ks[2][32 * 128];   // 16 KB
  __shared__ __align__(16) short Vs[2][6 * 512];    // 12 KB
  __shared__ __align__(16) short RH[64 * 28];       // 3.5 KB
  __shared__ __align__(16) short RW[64 * 28];       // 3.5 KB
  __shared__ __align__(16) short Ps[4][512];        // 4 KB

  // XCD-aware swizzle: 3200 blocks, 8 XCDs, 400/XCD -> contiguous bh chunks
  const int bid = blockIdx.x;
  const int swz = (bid & 7) * 400 + (bid >> 3);
  const int bh = swz / 50;
  const int qt = swz % 50;
  const int qbase = qt * 64;
  const int tid = threadIdx.x;
  const int wid = tid >> 6;
  const int lane = tid & 63;
  const int g = lane >> 4;
  const int kl = lane & 15;
  const int bb = bh >> 3, hh = bh & 7;
  const float scale = 0.10206207261596575f;

  const bf16* Qbh = Qp + (size_t)bh * NTOK * HD;
  const bf16* Kbh = Kp + (size_t)bh * NKEY * HD;
  const bf16* Vbh = Vp + (size_t)bh * NKEY * HD;

  // ---- stage rel tables (coalesced uint2) ----
  {
    const uint2* srcH = (const uint2*)(RHg + ((size_t)bh * NTOK + qbase) * 28);
    const uint2* srcW = (const uint2*)(RWg + ((size_t)bh * NTOK + qbase) * 28);
    for (int i = tid; i < 448; i += 256) {
      ((uint2*)RH)[i] = srcH[i];
      ((uint2*)RW)[i] = srcW[i];
    }
  }

  // ---- Q fragments direct from global ----
  s16x8 qf[3];
  {
    int qg = qbase + wid * 16 + kl; if (qg > NTOK - 1) qg = NTOK - 1;
    const bf16* qptr = Qbh + (size_t)qg * HD;
#pragma unroll
    for (int f = 0; f < 3; f++)
      qf[f] = *(const s16x8*)(qptr + f * 32 + g * 8);
  }

  auto stage_kv = [&](int t, int buf) {
    for (int idx = tid; idx < 384; idx += 256) {
      int kk = idx / 12, ch = idx % 12;
      int ks = t * 32 + kk; if (ks > 784) ks = 784;
      uint4 u = *(const uint4*)(Kbh + (size_t)ks * HD + ch * 8);
      *(uint4*)&Ks[buf][kk * 128 + ((ch ^ (kk & 7)) << 3)] = u;
      uint4 v = *(const uint4*)(Vbh + (size_t)ks * HD + ch * 8);
      *(uint4*)&Vs[buf][(ch >> 1) * 512 + kk * 16 + ((ch & 1) << 3)] = v;
    }
  };

  stage_kv(0, 0);
  __syncthreads();

  f32x4 o[6];
#pragma unroll
  for (int cb = 0; cb < 6; cb++) o[cb] = (f32x4){0.f, 0.f, 0.f, 0.f};
  float mrow[4] = {-1e30f, -1e30f, -1e30f, -1e30f};
  float lrow[4] = {0.f, 0.f, 0.f, 0.f};

  for (int t = 0; t < 25; t++) {
    const int buf = t & 1;
    if (t < 24) stage_kv(t + 1, buf ^ 1);

    f32x4 s0 = (f32x4){0.f, 0.f, 0.f, 0.f};
    f32x4 s1 = (f32x4){0.f, 0.f, 0.f, 0.f};
#pragma unroll
    for (int f = 0; f < 3; f++) {
      int ch = f * 4 + g;
      int r0 = kl, r1 = 16 + kl;
      s16x8 kf0 = *(const s16x8*)&Ks[buf][r0 * 128 + ((ch ^ (r0 & 7)) << 3)];
      s16x8 kf1 = *(const s16x8*)&Ks[buf][r1 * 128 + ((ch ^ (r1 & 7)) << 3)];
      s0 = __builtin_amdgcn_mfma_f32_16x16x32_bf16(qf[f], kf0, s0, 0, 0, 0);
      s1 = __builtin_amdgcn_mfma_f32_16x16x32_bf16(qf[f], kf1, s1, 0, 0, 0);
    }

    const int k0g = t * 32 + kl;
    const int k1g = k0g + 16;
    int ky0 = (k0g - 1) / 28, kx0 = (k0g - 1) % 28;
    if (kx0 < 0) kx0 = 0;
    int ky1 = (k1g - 1) / 28, kx1 = (k1g - 1) % 28;
    if (ky1 > 27) ky1 = 27;
    float lg0[4], lg1[4];
#pragma unroll
    for (int r = 0; r < 4; r++) {
      int ql = wid * 16 + g * 4 + r;
      int qg = qbase + ql;
      float rel0 = (qg > 0 && k0g > 0) ? s2f(RH[ql * 28 + ky0]) + s2f(RW[ql * 28 + kx0]) : 0.f;
      float rel1 = (qg > 0) ? s2f(RH[ql * 28 + ky1]) + s2f(RW[ql * 28 + kx1]) : 0.f;
      lg0[r] = s0[r] * scale + rel0;
      lg1[r] = (k1g < NKEY) ? (s1[r] * scale + rel1) : -1e30f;
    }

    float tm[4], al[4], p0[4], p1[4], rs[4];
#pragma unroll
    for (int r = 0; r < 4; r++) tm[r] = fmaxf(lg0[r], lg1[r]);
#pragma unroll
    for (int off = 1; off < 16; off <<= 1)
#pragma unroll
      for (int r = 0; r < 4; r++) tm[r] = fmaxf(tm[r], __shfl_xor(tm[r], off));
#pragma unroll
    for (int r = 0; r < 4; r++) {
      float mn = fmaxf(mrow[r], tm[r]);
      al[r] = __expf(mrow[r] - mn);
      p0[r] = __expf(lg0[r] - mn);
      p1[r] = __expf(lg1[r] - mn);
      mrow[r] = mn;
      rs[r] = p0[r] + p1[r];
    }
#pragma unroll
    for (int off = 1; off < 16; off <<= 1)
#pragma unroll
      for (int r = 0; r < 4; r++) rs[r] += __shfl_xor(rs[r], off);
#pragma unroll
    for (int r = 0; r < 4; r++) lrow[r] = lrow[r] * al[r] + rs[r];
#pragma unroll
    for (int cb = 0; cb < 6; cb++)
#pragma unroll
      for (int r = 0; r < 4; r++) o[cb][r] *= al[r];

    short* pw = &Ps[wid][0];
#pragma unroll
    for (int r = 0; r < 4; r++) {
      int q = g * 4 + r;
      int sw = (q >> 1) & 3;
      pw[q * 32 + (((kl >> 3) ^ sw) << 3) + (kl & 7)] = f2bs(p0[r]);
      int k1 = 16 + kl;
      pw[q * 32 + (((k1 >> 3) ^ sw) << 3) + (kl & 7)] = f2bs(p1[r]);
    }
    s16x8 pa = *(const s16x8*)(pw + kl * 32 + ((g ^ ((kl >> 1) & 3)) << 3));

    uint32_t vbase = (uint32_t)(size_t)&Vs[buf][0] + (uint32_t)(g * 256 + kl * 8);
    s16x4 tv[12];
#pragma unroll
    for (int cb = 0; cb < 6; cb++) {
      uint32_t va = vbase + cb * 1024;
      asm volatile("ds_read_b64_tr_b16 %0, %1" : "=v"(tv[2 * cb]) : "v"(va));
      asm volatile("ds_read_b64_tr_b16 %0, %1 offset:128" : "=v"(tv[2 * cb + 1]) : "v"(va));
    }
    asm volatile("s_waitcnt lgkmcnt(0)" ::: "memory");
    __builtin_amdgcn_sched_barrier(0);
#pragma unroll
    for (int cb = 0; cb < 6; cb++) {
      s16x8 vf = __builtin_shufflevector(tv[2 * cb], tv[2 * cb + 1], 0, 1, 2, 3, 4, 5, 6, 7);
      o[cb] = __builtin_amdgcn_mfma_f32_16x16x32_bf16(pa, vf, o[cb], 0, 0, 0);
    }
    __syncthreads();
  }

  // ---- epilogue: normalize + residual (from global) + transposed store ----
  float inv[4];
#pragma unroll
  for (int r = 0; r < 4; r++) inv[r] = 1.f / lrow[r];
#pragma unroll
  for (int cb = 0; cb < 6; cb++) {
#pragma unroll
    for (int r = 0; r < 4; r++) {
      int ql = wid * 16 + g * 4 + r;
      int qg = qbase + ql;
      if (qg < NTOK) {
        int c = cb * 16 + kl;
        float val = o[cb][r] * inv[r] + b2f(Qbh[(size_t)qg * HD + c]);
        out[((size_t)bb * NTOK + qg) * 768 + hh * 96 + c] = val;
      }
    }
  }
}

// ---------------- launch ----------------
extern "C" void kernel_launch(void* const* d_in, const int* in_sizes, int n_in,
                              void* d_out, int out_size, void* d_ws, size_t ws_size,
                              hipStream_t stream) {
  const float* x = (const float*)d_in[0];
  const float* qkv_w = (const float*)d_in[1];
  const float* qkv_b = (const float*)d_in[2];
  const float* pqw = (const float*)d_in[3];
  const float* pkw = (const float*)d_in[4];
  const float* pvw = (const float*)d_in[5];
  const float* nqg = (const float*)d_in[6];
  const float* nqb = (const float*)d_in[7];
  const float* nkg = (const float*)d_in[8];
  const float* nkb = (const float*)d_in[9];
  const float* nvg = (const float*)d_in[10];
  const float* nvb = (const float*)d_in[11];
  const float* relH = (const float*)d_in[12];
  const float* relW = (const float*)d_in[13];

  const size_t SZQ = (size_t)MROWS * DIMC;             // 19,273,728 elems
  const size_t SZK = (size_t)BATCH * NH * NKEY * HD;   //  4,823,040 elems
  const size_t SZR = (size_t)BATCH * NH * NTOK * 28;   //  5,621,504 elems

  // ws (bf16): rawQ [0,SZQ) -> reused as RHg/RWg after poolQ;
  //            rawK/poolQ [SZQ,2SZQ) ; WbT->poolK [2SZQ,+SZK) ; poolV [+SZK).
  // d_out: [Xb bf16 SZQ][rawV bf16 SZQ], both dead before k_attn writes out.
  bf16* ws = (bf16*)d_ws;
  bf16* Xb   = (bf16*)d_out;
  bf16* rawV = (bf16*)d_out + SZQ;
  bf16* rawQ = ws;
  bf16* rawK = ws + SZQ;
  bf16* WbT  = ws + 2 * SZQ;
  bf16* poolK = ws + 2 * SZQ;
  bf16* poolV = poolK + SZK;
  bf16* poolQ = rawK;            // aliases rawK (dead after poolK kernel)
  bf16* RHg = ws;                // aliases rawQ (dead after poolQ kernel)
  bf16* RWg = ws + SZR;
  float* out = (float*)d_out;

  k_cvtX<<<2048, 256, 0, stream>>>(x, Xb, (int)(SZQ / 4));
  k_cvtW<<<dim3(DIM3 / 64, DIMC / 64), 256, 0, stream>>>(qkv_w, WbT);

  dim3 g1(DIM3 / 128, (MROWS + 127) / 128);   // (18, 197)
  k_qkv_mfma<<<g1, 256, 0, stream>>>(Xb, WbT, qkv_b, rawQ, rawK, rawV);

  k_pool<2, 28, 28><<<BATCH * NH * NKEY, 64, 0, stream>>>(rawK, pkw, nkg, nkb, poolK);
  k_pool<2, 28, 28><<<BATCH * NH * NKEY, 64, 0, stream>>>(rawV, pvw, nvg, nvb, poolV);
  k_pool<1, 56, 56><<<BATCH * NH * NTOK, 64, 0, stream>>>(rawQ, pqw, nqg, nqb, poolQ);

  k_rel<<<(int)(SZR / 256), 256, 0, stream>>>(poolQ, relH, relW, RHg, RWg);

  k_attn<<<64 * 50, 256, 0, stream>>>(poolQ, poolK, poolV, RHg, RWg, out);
}

// Round 7
// 745.946 us; speedup vs baseline: 1.5752x; 1.5752x over previous
//
#include <hip/hip_runtime.h>
#include <hip/hip_bf16.h>

typedef __hip_bfloat16 bf16;
typedef __attribute__((ext_vector_type(8))) short s16x8;
typedef __attribute__((ext_vector_type(4))) short s16x4;
typedef __attribute__((ext_vector_type(4))) float f32x4;

// Problem constants
#define BATCH 8
#define NH 8
#define NTOK 3137         // H*W+1
#define HD 96             // head dim
#define HH 56
#define WW 56
#define NKEY 785          // 28*28+1
#define DIMC 768
#define DIM3 2304
#define MROWS (BATCH * NTOK)   // 25096

__device__ __forceinline__ float b2f(bf16 x) { return __bfloat162float(x); }
__device__ __forceinline__ bf16 f2b(float x) { return __float2bfloat16(x); }
__device__ __forceinline__ float s2f(short s) {
  return __uint_as_float(((uint32_t)(uint16_t)s) << 16);
}
__device__ __forceinline__ short f2bs(float x) {
  bf16 h = __float2bfloat16(x);
  short s; __builtin_memcpy(&s, &h, 2); return s;
}
__device__ __forceinline__ void gload_lds16(const void* g, void* l) {
  __builtin_amdgcn_global_load_lds(
      (const __attribute__((address_space(1))) void*)g,
      (__attribute__((address_space(3))) void*)l, 16, 0, 0);
}

// ---------------- Kernel 0a: X fp32 -> bf16 ----------------
__global__ __launch_bounds__(256) void k_cvtX(const float* __restrict__ X,
                                              bf16* __restrict__ Xb, int n4) {
  for (int i = blockIdx.x * blockDim.x + threadIdx.x; i < n4;
       i += gridDim.x * blockDim.x) {
    float4 v = reinterpret_cast<const float4*>(X)[i];
    ushort4 o;
    o.x = (unsigned short)f2bs(v.x); o.y = (unsigned short)f2bs(v.y);
    o.z = (unsigned short)f2bs(v.z); o.w = (unsigned short)f2bs(v.w);
    reinterpret_cast<ushort4*>(Xb)[i] = o;
  }
}

// ---------------- Kernel 0b: W [768][2304] fp32 -> W^T [2304][768] bf16 ----------------
__global__ __launch_bounds__(256) void k_cvtW(const float* __restrict__ W,
                                              bf16* __restrict__ WbT) {
  __shared__ float T[64][65];
  const int n0 = blockIdx.x * 64;
  const int k0 = blockIdx.y * 64;
  const int tid = threadIdx.x;
#pragma unroll
  for (int i = 0; i < 16; i++) {
    int e = tid + i * 256;
    int r = e >> 6, c = e & 63;
    T[r][c] = W[(size_t)(k0 + r) * DIM3 + n0 + c];
  }
  __syncthreads();
#pragma unroll
  for (int i = 0; i < 16; i++) {
    int e = tid + i * 256;
    int r = e >> 6, c = e & 63;
    WbT[(size_t)(n0 + r) * DIMC + k0 + c] = f2b(T[c][r]);
  }
}

// ---------------- Kernel 0c: Brel [224][96] bf16 (rows 0..110 = relH, 112..222 = relW) ----
__global__ __launch_bounds__(256) void k_cvtRel(const float* __restrict__ relHt,
                                                const float* __restrict__ relWt,
                                                bf16* __restrict__ Brel) {
  int i = blockIdx.x * 256 + threadIdx.x;   // float4 index, 5376 total
  int elem = i * 4;
  int row = elem / HD, c = elem % HD;
  float4 v = {0.f, 0.f, 0.f, 0.f};
  if (row < 111) v = *(const float4*)(relHt + (size_t)row * HD + c);
  else if (row >= 112 && row < 223) v = *(const float4*)(relWt + (size_t)(row - 112) * HD + c);
  short4 o;
  o.x = f2bs(v.x); o.y = f2bs(v.y); o.z = f2bs(v.z); o.w = f2bs(v.w);
  *(short4*)((short*)Brel + elem) = o;
}

// ---------------- Kernel 1: QKV projection, bf16 MFMA (unchanged) ----------------
__global__ __launch_bounds__(256) void k_qkv_mfma(
    const bf16* __restrict__ Xb, const bf16* __restrict__ WbT,
    const float* __restrict__ bias,
    bf16* __restrict__ Q, bf16* __restrict__ K, bf16* __restrict__ V) {
  __shared__ __align__(16) short As[4 * 128 * 8];
  __shared__ __align__(16) short Bs[4 * 128 * 8];
  const int tid = threadIdx.x;
  const int wid = tid >> 6, lane = tid & 63;
  const int g = lane >> 4, kl = lane & 15;
  const int wm = wid >> 1, wn = wid & 1;
  const int row0 = blockIdx.y * 128;
  const int col0 = blockIdx.x * 128;

  f32x4 acc[4][4] = {};

  for (int k0 = 0; k0 < DIMC; k0 += 32) {
#pragma unroll
    for (int r = 0; r < 2; r++) {
      int slot = r * 256 + wid * 64 + lane;
      int sg = slot >> 7, sm = slot & 127;
      int mm = row0 + sm; if (mm > MROWS - 1) mm = MROWS - 1;
      const bf16* gpA = Xb + (size_t)mm * DIMC + k0 + sg * 8;
      short* lpA = As + ((r * 256 + wid * 64) << 3);
      gload_lds16(gpA, lpA);
      const bf16* gpB = WbT + (size_t)(col0 + sm) * DIMC + k0 + sg * 8;
      short* lpB = Bs + ((r * 256 + wid * 64) << 3);
      gload_lds16(gpB, lpB);
    }
    __syncthreads();

    s16x8 af[4], bf[4];
#pragma unroll
    for (int i = 0; i < 4; i++)
      af[i] = *(const s16x8*)&As[((g << 7) + wm * 64 + i * 16 + kl) << 3];
#pragma unroll
    for (int j = 0; j < 4; j++)
      bf[j] = *(const s16x8*)&Bs[((g << 7) + wn * 64 + j * 16 + kl) << 3];
#pragma unroll
    for (int i = 0; i < 4; i++)
#pragma unroll
      for (int j = 0; j < 4; j++)
        acc[i][j] = __builtin_amdgcn_mfma_f32_16x16x32_bf16(af[i], bf[j], acc[i][j], 0, 0, 0);
    __syncthreads();
  }

#pragma unroll
  for (int i = 0; i < 4; i++) {
    int mbase = row0 + wm * 64 + i * 16 + (lane >> 4) * 4;
#pragma unroll
    for (int j = 0; j < 4; j++) {
      int n = col0 + wn * 64 + j * 16 + kl;
      int s = n / DIMC, rr = n % DIMC;
      int h = rr / HD, c = rr % HD;
      bf16* dst = (s == 0) ? Q : (s == 1) ? K : V;
      float bv = bias[n];
#pragma unroll
      for (int r = 0; r < 4; r++) {
        int mm = mbase + r;
        if (mm >= MROWS) continue;
        int b = mm / NTOK, nt = mm % NTOK;
        dst[(((size_t)b * NH + h) * NTOK + nt) * HD + c] = f2b(acc[i][j][r] + bv);
      }
    }
  }
}

// ---------------- Kernel 2: depthwise 3x3 pool + LayerNorm (unchanged) ----------------
template <int STRIDE, int OH, int OW>
__global__ __launch_bounds__(64) void k_pool(
    const bf16* __restrict__ raw, const float* __restrict__ wgt,
    const float* __restrict__ gam, const float* __restrict__ bet,
    bf16* __restrict__ out) {
  const int ntok = OH * OW + 1;
  const int t = blockIdx.x % ntok;
  const int bh = blockIdx.x / ntok;
  const int lane = threadIdx.x;
  const bf16* src = raw + (size_t)bh * NTOK * HD;

  float v0 = 0.f, v1 = 0.f;
  if (t == 0) {
    v0 = b2f(src[lane]);
    if (lane < 32) v1 = b2f(src[64 + lane]);
  } else {
    int oy = (t - 1) / OW, ox = (t - 1) % OW;
#pragma unroll
    for (int dy = 0; dy < 3; dy++) {
      int iy = oy * STRIDE + dy - 1;
      if (iy < 0 || iy >= HH) continue;
#pragma unroll
      for (int dx = 0; dx < 3; dx++) {
        int ix = ox * STRIDE + dx - 1;
        if (ix < 0 || ix >= WW) continue;
        const bf16* p = src + (size_t)(1 + iy * WW + ix) * HD;
        const float* wp = wgt + (dy * 3 + dx) * HD;
        v0 += b2f(p[lane]) * wp[lane];
        if (lane < 32) v1 += b2f(p[64 + lane]) * wp[64 + lane];
      }
    }
  }
  float s = v0 + ((lane < 32) ? v1 : 0.f);
  float s2 = v0 * v0 + ((lane < 32) ? v1 * v1 : 0.f);
#pragma unroll
  for (int o = 32; o > 0; o >>= 1) {
    s += __shfl_xor(s, o);
    s2 += __shfl_xor(s2, o);
  }
  float mean = s * (1.f / 96.f);
  float var = s2 * (1.f / 96.f) - mean * mean;
  float rstd = rsqrtf(var + 1e-5f);

  bf16* dst = out + ((size_t)bh * ntok + t) * HD;
  dst[lane] = f2b((v0 - mean) * rstd * gam[lane] + bet[lane]);
  if (lane < 32) dst[64 + lane] = f2b((v1 - mean) * rstd * gam[64 + lane] + bet[64 + lane]);
}

// ---------------- Kernel 2b: rel tables via MFMA ----------------
// P[row][col] = poolQ[row] . Brel[col]  (row = bh*NTOK+q, col in [0,224))
// then gather RHg[row][j] = P[row][ih(qy,j)], RWg[row][j] = P[row][112+iw(qx,j)].
// 64 rows/block, M = 200768 = 64*3137 exactly.
__global__ __launch_bounds__(256) void k_relmm(
    const bf16* __restrict__ Qp, const bf16* __restrict__ Brel,
    bf16* __restrict__ RHg, bf16* __restrict__ RWg) {
  __shared__ __align__(16) short L[64 * 104 + 224 * 104];   // 59904 B
  short* As = L;                 // [64][104]
  short* Bs = L + 64 * 104;      // [224][104]
  short* Sf = L;                 // overlay after compute: [64][224] = 28672 B

  const int tid = threadIdx.x;
  const int wid = tid >> 6, lane = tid & 63;
  const int g = lane >> 4, kl = lane & 15;
  const size_t row0 = (size_t)blockIdx.x * 64;

  // stage A: 64 x 96 bf16
  for (int i = tid; i < 768; i += 256) {
    int r = i / 12, ch = i % 12;
    *(uint4*)&As[r * 104 + ch * 8] = *(const uint4*)(Qp + (row0 + r) * HD + ch * 8);
  }
  // stage B: 224 x 96 bf16
  for (int i = tid; i < 2688; i += 256) {
    int r = i / 12, ch = i % 12;
    *(uint4*)&Bs[r * 104 + ch * 8] = *(const uint4*)((const short*)Brel + r * HD + ch * 8);
  }
  __syncthreads();

  // compute: wave wid -> rows wid*16..+16, 14 col-frags of 16
  s16x8 af[3];
#pragma unroll
  for (int kb = 0; kb < 3; kb++)
    af[kb] = *(const s16x8*)&As[(wid * 16 + kl) * 104 + kb * 32 + g * 8];
  f32x4 acc[14];
#pragma unroll
  for (int cf = 0; cf < 14; cf++) {
    f32x4 a = (f32x4){0.f, 0.f, 0.f, 0.f};
#pragma unroll
    for (int kb = 0; kb < 3; kb++) {
      s16x8 bfr = *(const s16x8*)&Bs[(cf * 16 + kl) * 104 + kb * 32 + g * 8];
      a = __builtin_amdgcn_mfma_f32_16x16x32_bf16(af[kb], bfr, a, 0, 0, 0);
    }
    acc[cf] = a;
  }
  __syncthreads();

  // write S [64][224] (C/D: col=lane&15, row=(lane>>4)*4+r)
#pragma unroll
  for (int cf = 0; cf < 14; cf++)
#pragma unroll
    for (int r = 0; r < 4; r++)
      Sf[(wid * 16 + g * 4 + r) * 224 + cf * 16 + kl] = f2bs(acc[cf][r]);
  __syncthreads();

  // gather 64 q x 28 j for both tables
  for (int i = tid; i < 1792; i += 256) {
    int ql = i / 28, j = i % 28;
    size_t row = row0 + ql;
    int q = (int)(row % NTOK);
    int qy, qx;
    if (q < 1) { qy = 0; qx = 0; } else { qy = (q - 1) / WW; qx = (q - 1) % WW; }
    int ih = qy - 2 * j + 54; ih = ih < 0 ? 0 : (ih > 110 ? 110 : ih);
    int iw = qx - 2 * j + 54; iw = iw < 0 ? 0 : (iw > 110 ? 110 : iw);
    ((short*)RHg)[row * 28 + j] = Sf[ql * 224 + ih];
    ((short*)RWg)[row * 28 + j] = Sf[ql * 224 + 112 + iw];
  }
}

// ---------------- Kernel 3: MFMA flash attention v2 (unchanged) ----------------
__global__ __launch_bounds__(256, 4) void k_attn(
    const bf16* __restrict__ Qp, const bf16* __restrict__ Kp,
    const bf16* __restrict__ Vp, const bf16* __restrict__ RHg,
    const bf16* __restrict__ RWg, float* __restrict__ out) {
  __shared__ __align__(16) short Ks[2][32 * 128];
  __shared__ __align__(16) short Vs[2][6 * 512];
  __shared__ __align__(16) short RH[64 * 28];
  __shared__ __align__(16) short RW[64 * 28];
  __shared__ __align__(16) short Ps[4][512];

  const int bid = blockIdx.x;
  const int swz = (bid & 7) * 400 + (bid >> 3);
  const int bh = swz / 50;
  const int qt = swz % 50;
  const int qbase = qt * 64;
  const int tid = threadIdx.x;
  const int wid = tid >> 6;
  const int lane = tid & 63;
  const int g = lane >> 4;
  const int kl = lane & 15;
  const int bb = bh >> 3, hh = bh & 7;
  const float scale = 0.10206207261596575f;

  const bf16* Qbh = Qp + (size_t)bh * NTOK * HD;
  const bf16* Kbh = Kp + (size_t)bh * NKEY * HD;
  const bf16* Vbh = Vp + (size_t)bh * NKEY * HD;

  {
    const uint2* srcH = (const uint2*)(RHg + ((size_t)bh * NTOK + qbase) * 28);
    const uint2* srcW = (const uint2*)(RWg + ((size_t)bh * NTOK + qbase) * 28);
    for (int i = tid; i < 448; i += 256) {
      ((uint2*)RH)[i] = srcH[i];
      ((uint2*)RW)[i] = srcW[i];
    }
  }

  s16x8 qf[3];
  {
    int qg = qbase + wid * 16 + kl; if (qg > NTOK - 1) qg = NTOK - 1;
    const bf16* qptr = Qbh + (size_t)qg * HD;
#pragma unroll
    for (int f = 0; f < 3; f++)
      qf[f] = *(const s16x8*)(qptr + f * 32 + g * 8);
  }

  auto stage_kv = [&](int t, int buf) {
    for (int idx = tid; idx < 384; idx += 256) {
      int kk = idx / 12, ch = idx % 12;
      int ks = t * 32 + kk; if (ks > 784) ks = 784;
      uint4 u = *(const uint4*)(Kbh + (size_t)ks * HD + ch * 8);
      *(uint4*)&Ks[buf][kk * 128 + ((ch ^ (kk & 7)) << 3)] = u;
      uint4 v = *(const uint4*)(Vbh + (size_t)ks * HD + ch * 8);
      *(uint4*)&Vs[buf][(ch >> 1) * 512 + kk * 16 + ((ch & 1) << 3)] = v;
    }
  };

  stage_kv(0, 0);
  __syncthreads();

  f32x4 o[6];
#pragma unroll
  for (int cb = 0; cb < 6; cb++) o[cb] = (f32x4){0.f, 0.f, 0.f, 0.f};
  float mrow[4] = {-1e30f, -1e30f, -1e30f, -1e30f};
  float lrow[4] = {0.f, 0.f, 0.f, 0.f};

  for (int t = 0; t < 25; t++) {
    const int buf = t & 1;
    if (t < 24) stage_kv(t + 1, buf ^ 1);

    f32x4 s0 = (f32x4){0.f, 0.f, 0.f, 0.f};
    f32x4 s1 = (f32x4){0.f, 0.f, 0.f, 0.f};
#pragma unroll
    for (int f = 0; f < 3; f++) {
      int ch = f * 4 + g;
      int r0 = kl, r1 = 16 + kl;
      s16x8 kf0 = *(const s16x8*)&Ks[buf][r0 * 128 + ((ch ^ (r0 & 7)) << 3)];
      s16x8 kf1 = *(const s16x8*)&Ks[buf][r1 * 128 + ((ch ^ (r1 & 7)) << 3)];
      s0 = __builtin_amdgcn_mfma_f32_16x16x32_bf16(qf[f], kf0, s0, 0, 0, 0);
      s1 = __builtin_amdgcn_mfma_f32_16x16x32_bf16(qf[f], kf1, s1, 0, 0, 0);
    }

    const int k0g = t * 32 + kl;
    const int k1g = k0g + 16;
    int ky0 = (k0g - 1) / 28, kx0 = (k0g - 1) % 28;
    if (kx0 < 0) kx0 = 0;
    int ky1 = (k1g - 1) / 28, kx1 = (k1g - 1) % 28;
    if (ky1 > 27) ky1 = 27;
    float lg0[4], lg1[4];
#pragma unroll
    for (int r = 0; r < 4; r++) {
      int ql = wid * 16 + g * 4 + r;
      int qg = qbase + ql;
      float rel0 = (qg > 0 && k0g > 0) ? s2f(RH[ql * 28 + ky0]) + s2f(RW[ql * 28 + kx0]) : 0.f;
      float rel1 = (qg > 0) ? s2f(RH[ql * 28 + ky1]) + s2f(RW[ql * 28 + kx1]) : 0.f;
      lg0[r] = s0[r] * scale + rel0;
      lg1[r] = (k1g < NKEY) ? (s1[r] * scale + rel1) : -1e30f;
    }

    float tm[4], al[4], p0[4], p1[4], rs[4];
#pragma unroll
    for (int r = 0; r < 4; r++) tm[r] = fmaxf(lg0[r], lg1[r]);
#pragma unroll
    for (int off = 1; off < 16; off <<= 1)
#pragma unroll
      for (int r = 0; r < 4; r++) tm[r] = fmaxf(tm[r], __shfl_xor(tm[r], off));
#pragma unroll
    for (int r = 0; r < 4; r++) {
      float mn = fmaxf(mrow[r], tm[r]);
      al[r] = __expf(mrow[r] - mn);
      p0[r] = __expf(lg0[r] - mn);
      p1[r] = __expf(lg1[r] - mn);
      mrow[r] = mn;
      rs[r] = p0[r] + p1[r];
    }
#pragma unroll
    for (int off = 1; off < 16; off <<= 1)
#pragma unroll
      for (int r = 0; r < 4; r++) rs[r] += __shfl_xor(rs[r], off);
#pragma unroll
    for (int r = 0; r < 4; r++) lrow[r] = lrow[r] * al[r] + rs[r];
#pragma unroll
    for (int cb = 0; cb < 6; cb++)
#pragma unroll
      for (int r = 0; r < 4; r++) o[cb][r] *= al[r];

    short* pw = &Ps[wid][0];
#pragma unroll
    for (int r = 0; r < 4; r++) {
      int q = g * 4 + r;
      int sw = (q >> 1) & 3;
      pw[q * 32 + (((kl >> 3) ^ sw) << 3) + (kl & 7)] = f2bs(p0[r]);
      int k1 = 16 + kl;
      pw[q * 32 + (((k1 >> 3) ^ sw) << 3) + (kl & 7)] = f2bs(p1[r]);
    }
    s16x8 pa = *(const s16x8*)(pw + kl * 32 + ((g ^ ((kl >> 1) & 3)) << 3));

    uint32_t vbase = (uint32_t)(size_t)&Vs[buf][0] + (uint32_t)(g * 256 + kl * 8);
    s16x4 tv[12];
#pragma unroll
    for (int cb = 0; cb < 6; cb++) {
      uint32_t va = vbase + cb * 1024;
      asm volatile("ds_read_b64_tr_b16 %0, %1" : "=v"(tv[2 * cb]) : "v"(va));
      asm volatile("ds_read_b64_tr_b16 %0, %1 offset:128" : "=v"(tv[2 * cb + 1]) : "v"(va));
    }
    asm volatile("s_waitcnt lgkmcnt(0)" ::: "memory");
    __builtin_amdgcn_sched_barrier(0);
#pragma unroll
    for (int cb = 0; cb < 6; cb++) {
      s16x8 vf = __builtin_shufflevector(tv[2 * cb], tv[2 * cb + 1], 0, 1, 2, 3, 4, 5, 6, 7);
      o[cb] = __builtin_amdgcn_mfma_f32_16x16x32_bf16(pa, vf, o[cb], 0, 0, 0);
    }
    __syncthreads();
  }

  float inv[4];
#pragma unroll
  for (int r = 0; r < 4; r++) inv[r] = 1.f / lrow[r];
#pragma unroll
  for (int cb = 0; cb < 6; cb++) {
#pragma unroll
    for (int r = 0; r < 4; r++) {
      int ql = wid * 16 + g * 4 + r;
      int qg = qbase + ql;
      if (qg < NTOK) {
        int c = cb * 16 + kl;
        float val = o[cb][r] * inv[r] + b2f(Qbh[(size_t)qg * HD + c]);
        out[((size_t)bb * NTOK + qg) * 768 + hh * 96 + c] = val;
      }
    }
  }
}

// ---------------- launch ----------------
extern "C" void kernel_launch(void* const* d_in, const int* in_sizes, int n_in,
                              void* d_out, int out_size, void* d_ws, size_t ws_size,
                              hipStream_t stream) {
  const float* x = (const float*)d_in[0];
  const float* qkv_w = (const float*)d_in[1];
  const float* qkv_b = (const float*)d_in[2];
  const float* pqw = (const float*)d_in[3];
  const float* pkw = (const float*)d_in[4];
  const float* pvw = (const float*)d_in[5];
  const float* nqg = (const float*)d_in[6];
  const float* nqb = (const float*)d_in[7];
  const float* nkg = (const float*)d_in[8];
  const float* nkb = (const float*)d_in[9];
  const float* nvg = (const float*)d_in[10];
  const float* nvb = (const float*)d_in[11];
  const float* relH = (const float*)d_in[12];
  const float* relW = (const float*)d_in[13];

  const size_t SZQ = (size_t)MROWS * DIMC;             // 19,273,728 elems
  const size_t SZK = (size_t)BATCH * NH * NKEY * HD;   //  4,823,040 elems
  const size_t SZR = (size_t)BATCH * NH * NTOK * 28;   //  5,621,504 elems

  // ws (bf16): rawQ [0,SZQ) -> reused as RHg/RWg/Brel after poolQ;
  //            rawK/poolQ [SZQ,2SZQ) ; WbT->poolK [2SZQ,+SZK) ; poolV [+SZK).
  // d_out: [Xb bf16 SZQ][rawV bf16 SZQ], both dead before k_attn writes out.
  bf16* ws = (bf16*)d_ws;
  bf16* Xb   = (bf16*)d_out;
  bf16* rawV = (bf16*)d_out + SZQ;
  bf16* rawQ = ws;
  bf16* rawK = ws + SZQ;
  bf16* WbT  = ws + 2 * SZQ;
  bf16* poolK = ws + 2 * SZQ;
  bf16* poolV = poolK + SZK;
  bf16* poolQ = rawK;            // aliases rawK (dead after poolK kernel)
  bf16* RHg  = ws;               // aliases rawQ (dead after poolQ kernel)
  bf16* RWg  = ws + SZR;
  bf16* Brel = ws + 2 * SZR;     // 224*96 elems, still inside old rawQ region
  float* out = (float*)d_out;

  k_cvtX<<<2048, 256, 0, stream>>>(x, Xb, (int)(SZQ / 4));
  k_cvtW<<<dim3(DIM3 / 64, DIMC / 64), 256, 0, stream>>>(qkv_w, WbT);

  dim3 g1(DIM3 / 128, (MROWS + 127) / 128);   // (18, 197)
  k_qkv_mfma<<<g1, 256, 0, stream>>>(Xb, WbT, qkv_b, rawQ, rawK, rawV);

  k_pool<2, 28, 28><<<BATCH * NH * NKEY, 64, 0, stream>>>(rawK, pkw, nkg, nkb, poolK);
  k_pool<2, 28, 28><<<BATCH * NH * NKEY, 64, 0, stream>>>(rawV, pvw, nvg, nvb, poolV);
  k_pool<1, 56, 56><<<BATCH * NH * NTOK, 64, 0, stream>>>(rawQ, pqw, nqg, nqb, poolQ);

  k_cvtRel<<<21, 256, 0, stream>>>(relH, relW, Brel);
  k_relmm<<<(MROWS * NH) / 64 /* 3137*... = 200768/64 = 3137 */, 256, 0, stream>>>(
      poolQ, Brel, RHg, RWg);

  k_attn<<<64 * 50, 256, 0, stream>>>(poolQ, poolK, poolV, RHg, RWg, out);
}